// Round 2
// baseline (4298.573 us; speedup 1.0000x reference)
//
#include <hip/hip_runtime.h>
#include <math.h>

#define T 128      // num_steps
#define U 128      // upsample_steps
#define TT 256     // total samples after merge
#define GEO 15
#define GSTR 17    // geo row stride (odd -> conflict-friendly)

__device__ __forceinline__ float softplus_f(float x) {
    return fmaxf(x, 0.0f) + log1pf(expf(-fabsf(x)));
}

__device__ __forceinline__ float sigmoid_f(float x) {
    return 1.0f / (1.0f + expf(-x));
}

// inclusive Hillis-Steele scans over LDS array s[0..n); all 256 threads must call
__device__ __forceinline__ void scan_mul(float* s, int n, int tid) {
    __syncthreads();
    for (int off = 1; off < n; off <<= 1) {
        bool act = (tid < n) && (tid >= off);
        float v = 0.0f;
        if (act) v = s[tid - off];
        __syncthreads();
        if (act) s[tid] *= v;
        __syncthreads();
    }
}

__device__ __forceinline__ void scan_add(float* s, int n, int tid) {
    __syncthreads();
    for (int off = 1; off < n; off <<= 1) {
        bool act = (tid < n) && (tid >= off);
        float v = 0.0f;
        if (act) v = s[tid - off];
        __syncthreads();
        if (act) s[tid] += v;
        __syncthreads();
    }
}

// density MLP: x(3) -> relu(64) -> 16 ; weights read with uniform indices (s_load)
__device__ __forceinline__ void density_mlp(
    float x0, float x1, float x2,
    const float* __restrict__ Wd1, const float* __restrict__ bd1,
    const float* __restrict__ Wd2, const float* __restrict__ bd2,
    float* __restrict__ geo_row, float* __restrict__ sigma_out)
{
    float h[64];
    #pragma unroll
    for (int j = 0; j < 64; ++j) {
        float a = fmaf(x0, Wd1[j], fmaf(x1, Wd1[64 + j], fmaf(x2, Wd1[128 + j], bd1[j])));
        h[j] = fmaxf(a, 0.0f);
    }
    float o[16];
    #pragma unroll
    for (int m = 0; m < 16; ++m) o[m] = bd2[m];
    #pragma unroll
    for (int j = 0; j < 64; ++j) {
        #pragma unroll
        for (int m = 0; m < 16; ++m) o[m] = fmaf(h[j], Wd2[j * 16 + m], o[m]);
    }
    *sigma_out = softplus_f(o[0]);
    #pragma unroll
    for (int k = 0; k < GEO; ++k) geo_row[k] = o[1 + k];
}

__global__ void __launch_bounds__(256)
nerf_render_kernel(
    const float* __restrict__ rays_o, const float* __restrict__ rays_d,
    const float* __restrict__ Wd1, const float* __restrict__ bd1,
    const float* __restrict__ Wd2, const float* __restrict__ bd2,
    const float* __restrict__ Wc1, const float* __restrict__ bc1,
    const float* __restrict__ Wc2, const float* __restrict__ bc2,
    float* __restrict__ out, int N)
{
    const int ray = blockIdx.x;
    const int tid = threadIdx.x;

    __shared__ float s_geo[TT][GSTR];
    __shared__ float s_sigma[TT];
    __shared__ float s_z[TT];     // [0..127] coarse z, [128..255] fine z
    __shared__ float s_zs[TT];    // sorted z
    __shared__ int   s_perm[TT];  // sorted position -> original index
    __shared__ float s_scan[TT];  // scan scratch
    __shared__ float s_wc[T];     // coarse weights
    __shared__ float s_cdf[T];    // 127 entries used
    __shared__ float s_bins[T];   // 127 entries used (z_mid)
    __shared__ float s_red[4][5]; // cross-wave reduction

    // --- ray data (uniform across block -> scalar loads) ---
    const float ox = rays_o[ray * 3 + 0], oy = rays_o[ray * 3 + 1], oz = rays_o[ray * 3 + 2];
    const float dx = rays_d[ray * 3 + 0], dy = rays_d[ray * 3 + 1], dz = rays_d[ray * 3 + 2];

    // --- near/far slab test ---
    const float ivx = 1.0f / dx, ivy = 1.0f / dy, ivz = 1.0f / dz;
    const float t1x = (-1.0f - ox) * ivx, t2x = (1.0f - ox) * ivx;
    const float t1y = (-1.0f - oy) * ivy, t2y = (1.0f - oy) * ivy;
    const float t1z = (-1.0f - oz) * ivz, t2z = (1.0f - oz) * ivz;
    const float tmin = fmaxf(fmaxf(fminf(t1x, t2x), fminf(t1y, t2y)), fminf(t1z, t2z));
    const float tmax = fminf(fminf(fmaxf(t1x, t2x), fmaxf(t1y, t2y)), fmaxf(t1z, t2z));
    const float nearv = fmaxf(tmin, 0.2f);
    const float farv  = fmaxf(tmax, nearv + 1e-4f);
    const float span  = farv - nearv;
    const float sample_dist = span * (1.0f / 128.0f);

    // --- Phase A: coarse samples + density ---
    if (tid < T) {
        float frac = (float)tid * (1.0f / 127.0f);
        float zv = nearv + span * frac;
        s_z[tid] = zv;
        float x0 = fminf(fmaxf(fmaf(dx, zv, ox), -1.0f), 1.0f);
        float x1 = fminf(fmaxf(fmaf(dy, zv, oy), -1.0f), 1.0f);
        float x2 = fminf(fmaxf(fmaf(dz, zv, oz), -1.0f), 1.0f);
        float sg;
        density_mlp(x0, x1, x2, Wd1, bd1, Wd2, bd2, &s_geo[tid][0], &sg);
        s_sigma[tid] = sg;
    }
    __syncthreads();

    // --- Phase B: coarse alpha weights ---
    float alpha_c = 0.0f;
    if (tid < T) {
        float delta = (tid < T - 1) ? (s_z[tid + 1] - s_z[tid]) : sample_dist;
        alpha_c = 1.0f - expf(-delta * s_sigma[tid]);
        s_scan[tid] = 1.0f - alpha_c + 1e-15f;
    }
    scan_mul(s_scan, T, tid);
    if (tid < T) {
        float Texcl = (tid == 0) ? 1.0f : s_scan[tid - 1];
        s_wc[tid] = alpha_c * Texcl;
    }
    __syncthreads();

    // --- Phase C: pdf -> cdf (126 weights), bins (127 mids) ---
    if (tid < 126) s_scan[tid] = s_wc[tid + 1] + 1e-5f;
    if (tid < 127) s_bins[tid] = s_z[tid] + 0.5f * (s_z[tid + 1] - s_z[tid]);
    scan_add(s_scan, 126, tid);
    {
        float invS = 1.0f / s_scan[125];
        if (tid < 126) s_cdf[tid + 1] = s_scan[tid] * invS;
        if (tid == 0) s_cdf[0] = 0.0f;
    }
    __syncthreads();

    // --- Phase D: inverse-CDF sampling + fine density ---
    if (tid < U) {
        float u = (1.0f + 2.0f * (float)tid) * (1.0f / 256.0f);
        // upper_bound over cdf[0..126]  (side='right')
        int lo = 0, hi = 127;
        while (lo < hi) { int mid = (lo + hi) >> 1; if (s_cdf[mid] <= u) lo = mid + 1; else hi = mid; }
        int below = lo - 1;             // >=0 since cdf[0]=0<=u
        int above = (lo < 127) ? lo : 126;
        float cg0 = s_cdf[below], cg1 = s_cdf[above];
        float bg0 = s_bins[below], bg1 = s_bins[above];
        float den = cg1 - cg0; if (den < 1e-5f) den = 1.0f;
        float tt = (u - cg0) / den;
        float nz = fmaf(tt, bg1 - bg0, bg0);
        s_z[T + tid] = nz;
        float x0 = fminf(fmaxf(fmaf(dx, nz, ox), -1.0f), 1.0f);
        float x1 = fminf(fmaxf(fmaf(dy, nz, oy), -1.0f), 1.0f);
        float x2 = fminf(fmaxf(fmaf(dz, nz, oz), -1.0f), 1.0f);
        float sg;
        density_mlp(x0, x1, x2, Wd1, bd1, Wd2, bd2, &s_geo[T + tid][0], &sg);
        s_sigma[T + tid] = sg;
    }
    __syncthreads();

    // --- Phase E: stable merge of two sorted 128-lists (merge-path ranks) ---
    {
        float v = s_z[tid];
        int rank;
        if (tid < T) {
            // coarse: rank = i + #{fine < v}   (stable: coarse first on ties)
            int lo = 0, hi = U;
            while (lo < hi) { int mid = (lo + hi) >> 1; if (s_z[T + mid] < v) lo = mid + 1; else hi = mid; }
            rank = tid + lo;
        } else {
            // fine: rank = j + #{coarse <= v}
            int lo = 0, hi = T;
            while (lo < hi) { int mid = (lo + hi) >> 1; if (s_z[mid] <= v) lo = mid + 1; else hi = mid; }
            rank = (tid - T) + lo;
        }
        s_perm[rank] = tid;
        s_zs[rank] = v;
    }
    __syncthreads();

    // --- Phase F: final alpha weights over 256 sorted samples ---
    float alpha_p, w_p;
    {
        float delta = (tid < TT - 1) ? (s_zs[tid + 1] - s_zs[tid]) : sample_dist;
        float sg = s_sigma[s_perm[tid]];
        alpha_p = 1.0f - expf(-delta * sg);
        s_scan[tid] = 1.0f - alpha_p + 1e-15f;
    }
    scan_mul(s_scan, TT, tid);
    w_p = alpha_p * ((tid == 0) ? 1.0f : s_scan[tid - 1]);

    // --- Phase G: color MLP (input = [rays_d(3), geo(15)]) ---
    float in[18];
    in[0] = dx; in[1] = dy; in[2] = dz;
    {
        int orig = s_perm[tid];
        #pragma unroll
        for (int k = 0; k < GEO; ++k) in[3 + k] = s_geo[orig][k];
    }
    float h[64];
    #pragma unroll
    for (int j = 0; j < 64; ++j) {
        float a = bc1[j];
        #pragma unroll
        for (int k = 0; k < 18; ++k) a = fmaf(in[k], Wc1[k * 64 + j], a);
        h[j] = fmaxf(a, 0.0f);
    }
    float o0 = bc2[0], o1 = bc2[1], o2 = bc2[2];
    #pragma unroll
    for (int j = 0; j < 64; ++j) {
        o0 = fmaf(h[j], Wc2[j * 3 + 0], o0);
        o1 = fmaf(h[j], Wc2[j * 3 + 1], o1);
        o2 = fmaf(h[j], Wc2[j * 3 + 2], o2);
    }
    float r = sigmoid_f(o0), g = sigmoid_f(o1), b = sigmoid_f(o2);

    // --- Phase H: weighted reductions ---
    float oriz = fminf(fmaxf((s_zs[tid] - nearv) / span, 0.0f), 1.0f);
    float c_ws = w_p;
    float c_dp = w_p * oriz;
    float c_r = w_p * r, c_g = w_p * g, c_b = w_p * b;
    #pragma unroll
    for (int off = 32; off > 0; off >>= 1) {
        c_ws += __shfl_down(c_ws, off);
        c_dp += __shfl_down(c_dp, off);
        c_r  += __shfl_down(c_r,  off);
        c_g  += __shfl_down(c_g,  off);
        c_b  += __shfl_down(c_b,  off);
    }
    __syncthreads();
    int wave = tid >> 6, lane = tid & 63;
    if (lane == 0) {
        s_red[wave][0] = c_ws; s_red[wave][1] = c_dp;
        s_red[wave][2] = c_r;  s_red[wave][3] = c_g; s_red[wave][4] = c_b;
    }
    __syncthreads();
    if (tid == 0) {
        float ws = 0.0f, dp = 0.0f, rr = 0.0f, gg = 0.0f, bb = 0.0f;
        #pragma unroll
        for (int wv = 0; wv < 4; ++wv) {
            ws += s_red[wv][0]; dp += s_red[wv][1];
            rr += s_red[wv][2]; gg += s_red[wv][3]; bb += s_red[wv][4];
        }
        float bgadd = 1.0f - ws;
        out[ray]             = dp;                 // depth [N]
        out[N + ray * 3 + 0] = rr + bgadd;         // image [N,3]
        out[N + ray * 3 + 1] = gg + bgadd;
        out[N + ray * 3 + 2] = bb + bgadd;
        out[4 * N + ray]     = ws;                 // weights_sum [N]
    }
}

extern "C" void kernel_launch(void* const* d_in, const int* in_sizes, int n_in,
                              void* d_out, int out_size, void* d_ws, size_t ws_size,
                              hipStream_t stream) {
    const float* rays_o = (const float*)d_in[0];
    const float* rays_d = (const float*)d_in[1];
    const float* Wd1 = (const float*)d_in[2];
    const float* bd1 = (const float*)d_in[3];
    const float* Wd2 = (const float*)d_in[4];
    const float* bd2 = (const float*)d_in[5];
    const float* Wc1 = (const float*)d_in[6];
    const float* bc1 = (const float*)d_in[7];
    const float* Wc2 = (const float*)d_in[8];
    const float* bc2 = (const float*)d_in[9];
    // d_in[10]/d_in[11] are num_steps/upsample_steps (=128/128), hardcoded.

    const int N = in_sizes[0] / 3;   // 32768 rays
    float* out = (float*)d_out;

    nerf_render_kernel<<<N, 256, 0, stream>>>(
        rays_o, rays_d, Wd1, bd1, Wd2, bd2, Wc1, bc1, Wc2, bc2, out, N);
}

// Round 7
// 1133.442 us; speedup vs baseline: 3.7925x; 3.7925x over previous
//
#include <hip/hip_runtime.h>
#include <math.h>

#define NTH 128    // threads per block (1 ray per block)
#define T 128      // num_steps
#define U 128      // upsample_steps
#define TT 256     // merged samples

__device__ __forceinline__ float softplus_f(float x) {
    return fmaxf(x, 0.0f) + log1pf(expf(-fabsf(x)));
}
__device__ __forceinline__ float sigmoid_f(float x) {
    return 1.0f / (1.0f + expf(-x));
}
__device__ __forceinline__ float clamp1(float x) {
    return fminf(fmaxf(x, -1.0f), 1.0f);
}

__global__ void __launch_bounds__(NTH)
nerf_render_kernel(
    const float* __restrict__ rays_o, const float* __restrict__ rays_d,
    const float* __restrict__ Wd1, const float* __restrict__ bd1,
    const float* __restrict__ Wd2, const float* __restrict__ bd2,
    const float* __restrict__ Wc1, const float* __restrict__ bc1,
    const float* __restrict__ Wc2, const float* __restrict__ bc2,
    float* __restrict__ out, int N)
{
    const int ray  = blockIdx.x;
    const int tid  = threadIdx.x;
    const int lane = tid & 63;
    const int wv   = tid >> 6;

    // ---- LDS: weights (broadcast-read) + per-ray state ----
    __shared__ float w1[192];        // Wd1 [3][64] as-is
    __shared__ float b1[64];
    __shared__ float w2[1024];       // Wd2 [64][16] as-is
    __shared__ float b2[16];
    __shared__ float c1[64 * 20];    // row j: Wc1[k][j] k=0..17, bias at [18], 0 at [19]
    __shared__ float c2[64 * 4];     // row j: Wc2[j][0..2], 0
    __shared__ float s_geo[TT][17];
    __shared__ float s_sigma[TT];
    __shared__ float s_z[TT];        // [0..127] coarse, [128..255] fine
    __shared__ float s_zs[TT];       // sorted
    __shared__ int   s_perm[TT];
    __shared__ float s_wc[T];
    __shared__ float s_cdf[T];       // 0..126 used
    __shared__ float s_bins[T];      // 0..126 used
    __shared__ float s_ct[4];        // chunk totals (final scan)
    __shared__ float s_tmp[4];       // wave totals (coarse scans)
    __shared__ float s_red[2][5];

    // ---- stage weights into LDS (coalesced, once per block) ----
    for (int i = tid; i < 192; i += NTH)  w1[i] = Wd1[i];
    for (int i = tid; i < 64; i += NTH)   b1[i] = bd1[i];
    for (int i = tid; i < 1024; i += NTH) w2[i] = Wd2[i];
    for (int i = tid; i < 16; i += NTH)   b2[i] = bd2[i];
    for (int i = tid; i < 64 * 20; i += NTH) {
        int j = i / 20, k = i - j * 20;
        c1[i] = (k < 18) ? Wc1[k * 64 + j] : ((k == 18) ? bc1[j] : 0.0f);
    }
    for (int i = tid; i < 256; i += NTH) {
        int j = i >> 2, c = i & 3;
        c2[i] = (c < 3) ? Wc2[j * 3 + c] : 0.0f;
    }

    // ---- ray data + slab test (uniform) ----
    const float ox = rays_o[ray * 3 + 0], oy = rays_o[ray * 3 + 1], oz = rays_o[ray * 3 + 2];
    const float dx = rays_d[ray * 3 + 0], dy = rays_d[ray * 3 + 1], dz = rays_d[ray * 3 + 2];
    const float ivx = 1.0f / dx, ivy = 1.0f / dy, ivz = 1.0f / dz;
    const float t1x = (-1.0f - ox) * ivx, t2x = (1.0f - ox) * ivx;
    const float t1y = (-1.0f - oy) * ivy, t2y = (1.0f - oy) * ivy;
    const float t1z = (-1.0f - oz) * ivz, t2z = (1.0f - oz) * ivz;
    const float tmin = fmaxf(fmaxf(fminf(t1x, t2x), fminf(t1y, t2y)), fminf(t1z, t2z));
    const float tmax = fminf(fminf(fmaxf(t1x, t2x), fmaxf(t1y, t2y)), fmaxf(t1z, t2z));
    const float nearv = fmaxf(tmin, 0.2f);
    const float farv  = fmaxf(tmax, nearv + 1e-4f);
    const float span  = farv - nearv;
    const float sample_dist = span * (1.0f / 128.0f);

    __syncthreads();   // weights staged

    // fused density MLP: LDS-broadcast weights, layer1+layer2 chunk-fused
    auto density_mlp = [&](float x0, float x1, float x2, float* geo_out, float* sig_out) {
        float o[16];
        {
            const float4* bp = (const float4*)b2;
            float4 q0 = bp[0], q1 = bp[1], q2 = bp[2], q3 = bp[3];
            o[0] = q0.x; o[1] = q0.y; o[2]  = q0.z; o[3]  = q0.w;
            o[4] = q1.x; o[5] = q1.y; o[6]  = q1.z; o[7]  = q1.w;
            o[8] = q2.x; o[9] = q2.y; o[10] = q2.z; o[11] = q2.w;
            o[12] = q3.x; o[13] = q3.y; o[14] = q3.z; o[15] = q3.w;
        }
        for (int jb = 0; jb < 16; ++jb) {   // not fully unrolled: keep icache small
            float4 wa  = *(const float4*)&w1[jb * 4];
            float4 wbv = *(const float4*)&w1[64 + jb * 4];
            float4 wcv = *(const float4*)&w1[128 + jb * 4];
            float4 bb  = *(const float4*)&b1[jb * 4];
            float hh[4];
            hh[0] = fmaxf(fmaf(x0, wa.x, fmaf(x1, wbv.x, fmaf(x2, wcv.x, bb.x))), 0.0f);
            hh[1] = fmaxf(fmaf(x0, wa.y, fmaf(x1, wbv.y, fmaf(x2, wcv.y, bb.y))), 0.0f);
            hh[2] = fmaxf(fmaf(x0, wa.z, fmaf(x1, wbv.z, fmaf(x2, wcv.z, bb.z))), 0.0f);
            hh[3] = fmaxf(fmaf(x0, wa.w, fmaf(x1, wbv.w, fmaf(x2, wcv.w, bb.w))), 0.0f);
            #pragma unroll
            for (int u = 0; u < 4; ++u) {
                const float4* r = (const float4*)&w2[(jb * 4 + u) * 16];
                float4 r0 = r[0], r1 = r[1], r2 = r[2], r3 = r[3];
                float h = hh[u];
                o[0]  = fmaf(h, r0.x, o[0]);  o[1]  = fmaf(h, r0.y, o[1]);
                o[2]  = fmaf(h, r0.z, o[2]);  o[3]  = fmaf(h, r0.w, o[3]);
                o[4]  = fmaf(h, r1.x, o[4]);  o[5]  = fmaf(h, r1.y, o[5]);
                o[6]  = fmaf(h, r1.z, o[6]);  o[7]  = fmaf(h, r1.w, o[7]);
                o[8]  = fmaf(h, r2.x, o[8]);  o[9]  = fmaf(h, r2.y, o[9]);
                o[10] = fmaf(h, r2.z, o[10]); o[11] = fmaf(h, r2.w, o[11]);
                o[12] = fmaf(h, r3.x, o[12]); o[13] = fmaf(h, r3.y, o[13]);
                o[14] = fmaf(h, r3.z, o[14]); o[15] = fmaf(h, r3.w, o[15]);
            }
        }
        *sig_out = softplus_f(o[0]);
        #pragma unroll
        for (int k = 0; k < 15; ++k) geo_out[k] = o[1 + k];
    };

    // ---- Phase A: coarse samples (128 threads, all active) ----
    float z_reg, sigma_reg;
    {
        float frac = (float)tid * (1.0f / 127.0f);
        z_reg = fmaf(span, frac, nearv);
        s_z[tid] = z_reg;
        float x0 = clamp1(fmaf(dx, z_reg, ox));
        float x1 = clamp1(fmaf(dy, z_reg, oy));
        float x2 = clamp1(fmaf(dz, z_reg, oz));
        density_mlp(x0, x1, x2, &s_geo[tid][0], &sigma_reg);
        s_sigma[tid] = sigma_reg;
    }
    __syncthreads();

    // ---- Phase B: coarse alpha weights (shuffle scan) ----
    {
        float delta = (tid < T - 1) ? (s_z[tid + 1] - z_reg) : sample_dist;
        float alpha = 1.0f - expf(-delta * sigma_reg);
        float inc = 1.0f - alpha + 1e-15f;
        #pragma unroll
        for (int off = 1; off < 64; off <<= 1) {
            float v = __shfl_up(inc, off);
            if (lane >= off) inc *= v;
        }
        if (lane == 63) s_tmp[wv] = inc;
        __syncthreads();
        float ex = __shfl_up(inc, 1);
        if (lane == 0) ex = 1.0f;
        if (wv == 1) ex *= s_tmp[0];
        s_wc[tid] = alpha * ex;
    }
    __syncthreads();

    // ---- Phase C: pdf -> cdf over w_coarse[1..126] + bins ----
    {
        float pv = (tid < 126) ? (s_wc[tid + 1] + 1e-5f) : 0.0f;
        float inc = pv;
        #pragma unroll
        for (int off = 1; off < 64; off <<= 1) {
            float v = __shfl_up(inc, off);
            if (lane >= off) inc += v;
        }
        if (lane == 63) s_tmp[2 + wv] = inc;
        __syncthreads();
        float tot = s_tmp[2] + s_tmp[3];
        float inv = 1.0f / tot;
        if (wv == 1) inc += s_tmp[2];
        if (tid < 126) s_cdf[tid + 1] = inc * inv;
        if (tid == 0)  s_cdf[0] = 0.0f;
        s_bins[tid] = (tid < 127) ? fmaf(0.5f, s_z[tid + 1] - z_reg, z_reg) : 0.0f;
    }
    __syncthreads();

    // ---- Phase D: inverse-CDF sampling + fine density (all active) ----
    {
        float u = (1.0f + 2.0f * (float)tid) * (1.0f / 256.0f);
        int lo = 0, hi = 127;
        while (lo < hi) { int mid = (lo + hi) >> 1; if (s_cdf[mid] <= u) lo = mid + 1; else hi = mid; }
        int below = lo - 1;
        int above = (lo < 127) ? lo : 126;
        float cg0 = s_cdf[below], cg1 = s_cdf[above];
        float bg0 = s_bins[below], bg1 = s_bins[above];
        float den = cg1 - cg0; if (den < 1e-5f) den = 1.0f;
        float tt2 = (u - cg0) / den;
        float nz = fmaf(tt2, bg1 - bg0, bg0);
        s_z[T + tid] = nz;
        float x0 = clamp1(fmaf(dx, nz, ox));
        float x1 = clamp1(fmaf(dy, nz, oy));
        float x2 = clamp1(fmaf(dz, nz, oz));
        float sg;
        density_mlp(x0, x1, x2, &s_geo[T + tid][0], &sg);
        s_sigma[T + tid] = sg;
    }
    __syncthreads();

    // ---- Phase E: stable merge (each thread places its coarse + fine item) ----
    {
        float vc = z_reg;
        int lo = 0, hi = U;
        while (lo < hi) { int mid = (lo + hi) >> 1; if (s_z[T + mid] < vc) lo = mid + 1; else hi = mid; }
        int rc = tid + lo;
        s_perm[rc] = tid; s_zs[rc] = vc;

        float vf = s_z[T + tid];
        lo = 0; hi = T;
        while (lo < hi) { int mid = (lo + hi) >> 1; if (s_z[mid] <= vf) lo = mid + 1; else hi = mid; }
        int rf = tid + lo;
        s_perm[rf] = T + tid; s_zs[rf] = vf;
    }
    __syncthreads();

    // ---- Phase F: final weights over 256 sorted samples (2 elems/thread) ----
    const int eA = wv * 64 + lane;         // chunk wv      (0..127)
    const int eB = 128 + wv * 64 + lane;   // chunk 2+wv    (128..255)
    float wA, wB, aA, aB;
    {
        float zA = s_zs[eA];
        float dA = s_zs[eA + 1] - zA;                       // eA+1 <= 128, valid
        float zB = s_zs[eB];
        float dB = (eB < TT - 1) ? (s_zs[eB + 1] - zB) : sample_dist;
        aA = 1.0f - expf(-dA * s_sigma[s_perm[eA]]);
        aB = 1.0f - expf(-dB * s_sigma[s_perm[eB]]);
        float tA = 1.0f - aA + 1e-15f;
        float tB = 1.0f - aB + 1e-15f;
        #pragma unroll
        for (int off = 1; off < 64; off <<= 1) {
            float vA = __shfl_up(tA, off);
            float vB = __shfl_up(tB, off);
            if (lane >= off) { tA *= vA; tB *= vB; }
        }
        if (lane == 63) { s_ct[wv] = tA; s_ct[2 + wv] = tB; }
        __syncthreads();
        float ct0 = s_ct[0], ct1 = s_ct[1], ct2 = s_ct[2];
        float exA = __shfl_up(tA, 1); if (lane == 0) exA = 1.0f;
        float exB = __shfl_up(tB, 1); if (lane == 0) exB = 1.0f;
        float pA = (wv == 0) ? 1.0f : ct0;
        float pB = ct0 * ct1 * ((wv == 0) ? 1.0f : ct2);
        wA = aA * exA * pA;
        wB = aB * exB * pB;
    }

    // ---- Phase G: color MLP, 2 samples/thread (R=2 weight reuse) ----
    float inA[20], inB[20];
    inA[0] = dx; inA[1] = dy; inA[2] = dz;
    inB[0] = dx; inB[1] = dy; inB[2] = dz;
    {
        int pa = s_perm[eA], pb = s_perm[eB];
        #pragma unroll
        for (int k = 0; k < 15; ++k) {
            inA[3 + k] = s_geo[pa][k];
            inB[3 + k] = s_geo[pb][k];
        }
    }
    inA[18] = 1.0f; inA[19] = 0.0f;   // bias slot, pad
    inB[18] = 1.0f; inB[19] = 0.0f;
    float o0A = bc2[0], o1A = bc2[1], o2A = bc2[2];
    float o0B = o0A, o1B = o1A, o2B = o2A;
    for (int j = 0; j < 64; ++j) {
        const float4* row = (const float4*)&c1[j * 20];
        float hA = 0.0f, hB = 0.0f;
        #pragma unroll
        for (int kb = 0; kb < 5; ++kb) {
            float4 rr = row[kb];
            hA = fmaf(inA[kb * 4 + 0], rr.x, hA);
            hA = fmaf(inA[kb * 4 + 1], rr.y, hA);
            hA = fmaf(inA[kb * 4 + 2], rr.z, hA);
            hA = fmaf(inA[kb * 4 + 3], rr.w, hA);
            hB = fmaf(inB[kb * 4 + 0], rr.x, hB);
            hB = fmaf(inB[kb * 4 + 1], rr.y, hB);
            hB = fmaf(inB[kb * 4 + 2], rr.z, hB);
            hB = fmaf(inB[kb * 4 + 3], rr.w, hB);
        }
        hA = fmaxf(hA, 0.0f);
        hB = fmaxf(hB, 0.0f);
        float4 q = *(const float4*)&c2[j * 4];
        o0A = fmaf(hA, q.x, o0A); o1A = fmaf(hA, q.y, o1A); o2A = fmaf(hA, q.z, o2A);
        o0B = fmaf(hB, q.x, o0B); o1B = fmaf(hB, q.y, o1B); o2B = fmaf(hB, q.z, o2B);
    }
    float rA = sigmoid_f(o0A), gA = sigmoid_f(o1A), bA = sigmoid_f(o2A);
    float rB = sigmoid_f(o0B), gB = sigmoid_f(o1B), bB = sigmoid_f(o2B);

    // ---- Phase H: weighted reductions ----
    float orizA = fminf(fmaxf((s_zs[eA] - nearv) / span, 0.0f), 1.0f);
    float orizB = fminf(fmaxf((s_zs[eB] - nearv) / span, 0.0f), 1.0f);
    float c_ws = wA + wB;
    float c_dp = wA * orizA + wB * orizB;
    float c_r  = wA * rA + wB * rB;
    float c_g  = wA * gA + wB * gB;
    float c_b  = wA * bA + wB * bB;
    #pragma unroll
    for (int off = 32; off > 0; off >>= 1) {
        c_ws += __shfl_down(c_ws, off);
        c_dp += __shfl_down(c_dp, off);
        c_r  += __shfl_down(c_r,  off);
        c_g  += __shfl_down(c_g,  off);
        c_b  += __shfl_down(c_b,  off);
    }
    __syncthreads();
    if (lane == 0) {
        s_red[wv][0] = c_ws; s_red[wv][1] = c_dp;
        s_red[wv][2] = c_r;  s_red[wv][3] = c_g; s_red[wv][4] = c_b;
    }
    __syncthreads();
    if (tid == 0) {
        float ws = s_red[0][0] + s_red[1][0];
        float dp = s_red[0][1] + s_red[1][1];
        float rr = s_red[0][2] + s_red[1][2];
        float gg = s_red[0][3] + s_red[1][3];
        float bb = s_red[0][4] + s_red[1][4];
        float bgadd = 1.0f - ws;
        out[ray]             = dp;
        out[N + ray * 3 + 0] = rr + bgadd;
        out[N + ray * 3 + 1] = gg + bgadd;
        out[N + ray * 3 + 2] = bb + bgadd;
        out[4 * N + ray]     = ws;
    }
}

extern "C" void kernel_launch(void* const* d_in, const int* in_sizes, int n_in,
                              void* d_out, int out_size, void* d_ws, size_t ws_size,
                              hipStream_t stream) {
    const float* rays_o = (const float*)d_in[0];
    const float* rays_d = (const float*)d_in[1];
    const float* Wd1 = (const float*)d_in[2];
    const float* bd1 = (const float*)d_in[3];
    const float* Wd2 = (const float*)d_in[4];
    const float* bd2 = (const float*)d_in[5];
    const float* Wc1 = (const float*)d_in[6];
    const float* bc1 = (const float*)d_in[7];
    const float* Wc2 = (const float*)d_in[8];
    const float* bc2 = (const float*)d_in[9];

    const int N = in_sizes[0] / 3;   // 32768 rays
    float* out = (float*)d_out;

    nerf_render_kernel<<<N, NTH, 0, stream>>>(
        rays_o, rays_d, Wd1, bd1, Wd2, bd2, Wc1, bc1, Wc2, bc2, out, N);
}

// Round 9
// 801.196 us; speedup vs baseline: 5.3652x; 1.4147x over previous
//
#include <hip/hip_runtime.h>
#include <math.h>

#define NTH 128    // threads per block (1 ray per block)
#define T 128      // num_steps
#define U 128      // upsample_steps
#define TT 256     // merged samples

__device__ __forceinline__ float softplus_f(float x) {
    return fmaxf(x, 0.0f) + log1pf(expf(-fabsf(x)));
}
__device__ __forceinline__ float sigmoid_f(float x) {
    return 1.0f / (1.0f + expf(-x));
}
__device__ __forceinline__ float clamp1(float x) {
    return fminf(fmaxf(x, -1.0f), 1.0f);
}
// fp32 -> bf16 (RNE) and back
__device__ __forceinline__ unsigned short f2bf(float f) {
    unsigned int u = __float_as_uint(f);
    unsigned int r = (u + 0x7FFFu + ((u >> 16) & 1u)) >> 16;
    return (unsigned short)r;
}
__device__ __forceinline__ float bf2f(unsigned short v) {
    return __uint_as_float(((unsigned int)v) << 16);
}

__global__ void __launch_bounds__(NTH)
nerf_render_kernel(
    const float* __restrict__ rays_o, const float* __restrict__ rays_d,
    const float* __restrict__ Wd1, const float* __restrict__ bd1,
    const float* __restrict__ Wd2, const float* __restrict__ bd2,
    const float* __restrict__ Wc1, const float* __restrict__ bc1,
    const float* __restrict__ Wc2, const float* __restrict__ bc2,
    float* __restrict__ out, int N)
{
    const int ray  = blockIdx.x;
    const int tid  = threadIdx.x;
    const int lane = tid & 63;
    const int wv   = tid >> 6;

    // ---- LDS: weights (broadcast-read) + per-ray state ----
    __shared__ float w1[192];        // Wd1 [3][64] as-is
    __shared__ float b1[64];
    __shared__ float w2[1024];       // Wd2 [64][16] as-is
    __shared__ float b2[16];
    __shared__ float c1[64 * 20];    // row j: Wc1[k][j] k=0..17, bias at [18], 0 at [19]
    __shared__ float c2[64 * 4];     // row j: Wc2[j][0..2], 0
    __shared__ unsigned short s_geo16[15][TT];  // bf16 geo, column-major (2-way banks both sides)
    __shared__ float s_sigma[TT];
    __shared__ float s_z[TT];        // [0..127] coarse, [128..255] fine
    __shared__ float s_zs[TT];       // sorted
    __shared__ int   s_perm[TT];
    __shared__ float s_wc[T];
    __shared__ float s_cdf[T];       // 0..126 used
    __shared__ float s_bins[T];      // 0..126 used
    __shared__ float s_ct[4];        // chunk totals (final scan)
    __shared__ float s_tmp[4];       // wave totals (coarse scans)
    __shared__ float s_red[2][5];

    // ---- stage weights into LDS (coalesced, once per block) ----
    for (int i = tid; i < 192; i += NTH)  w1[i] = Wd1[i];
    for (int i = tid; i < 64; i += NTH)   b1[i] = bd1[i];
    for (int i = tid; i < 1024; i += NTH) w2[i] = Wd2[i];
    for (int i = tid; i < 16; i += NTH)   b2[i] = bd2[i];
    for (int i = tid; i < 64 * 20; i += NTH) {
        int j = i / 20, k = i - j * 20;
        c1[i] = (k < 18) ? Wc1[k * 64 + j] : ((k == 18) ? bc1[j] : 0.0f);
    }
    for (int i = tid; i < 256; i += NTH) {
        int j = i >> 2, c = i & 3;
        c2[i] = (c < 3) ? Wc2[j * 3 + c] : 0.0f;
    }

    // ---- ray data + slab test (uniform) ----
    const float ox = rays_o[ray * 3 + 0], oy = rays_o[ray * 3 + 1], oz = rays_o[ray * 3 + 2];
    const float dx = rays_d[ray * 3 + 0], dy = rays_d[ray * 3 + 1], dz = rays_d[ray * 3 + 2];
    const float ivx = 1.0f / dx, ivy = 1.0f / dy, ivz = 1.0f / dz;
    const float t1x = (-1.0f - ox) * ivx, t2x = (1.0f - ox) * ivx;
    const float t1y = (-1.0f - oy) * ivy, t2y = (1.0f - oy) * ivy;
    const float t1z = (-1.0f - oz) * ivz, t2z = (1.0f - oz) * ivz;
    const float tmin = fmaxf(fmaxf(fminf(t1x, t2x), fminf(t1y, t2y)), fminf(t1z, t2z));
    const float tmax = fminf(fminf(fmaxf(t1x, t2x), fmaxf(t1y, t2y)), fmaxf(t1z, t2z));
    const float nearv = fmaxf(tmin, 0.2f);
    const float farv  = fmaxf(tmax, nearv + 1e-4f);
    const float span  = farv - nearv;
    const float sample_dist = span * (1.0f / 128.0f);

    __syncthreads();   // weights staged

    // fused density MLP: LDS-broadcast weights, layer1+layer2 chunk-fused.
    // geo written directly to bf16 column-major LDS for sample index si.
    auto density_mlp = [&](float x0, float x1, float x2, int si, float* sig_out) {
        float o[16];
        {
            const float4* bp = (const float4*)b2;
            float4 q0 = bp[0], q1 = bp[1], q2 = bp[2], q3 = bp[3];
            o[0] = q0.x; o[1] = q0.y; o[2]  = q0.z; o[3]  = q0.w;
            o[4] = q1.x; o[5] = q1.y; o[6]  = q1.z; o[7]  = q1.w;
            o[8] = q2.x; o[9] = q2.y; o[10] = q2.z; o[11] = q2.w;
            o[12] = q3.x; o[13] = q3.y; o[14] = q3.z; o[15] = q3.w;
        }
        for (int jb = 0; jb < 16; ++jb) {   // not fully unrolled: keep icache small
            float4 wa  = *(const float4*)&w1[jb * 4];
            float4 wbv = *(const float4*)&w1[64 + jb * 4];
            float4 wcv = *(const float4*)&w1[128 + jb * 4];
            float4 bb  = *(const float4*)&b1[jb * 4];
            float hh[4];
            hh[0] = fmaxf(fmaf(x0, wa.x, fmaf(x1, wbv.x, fmaf(x2, wcv.x, bb.x))), 0.0f);
            hh[1] = fmaxf(fmaf(x0, wa.y, fmaf(x1, wbv.y, fmaf(x2, wcv.y, bb.y))), 0.0f);
            hh[2] = fmaxf(fmaf(x0, wa.z, fmaf(x1, wbv.z, fmaf(x2, wcv.z, bb.z))), 0.0f);
            hh[3] = fmaxf(fmaf(x0, wa.w, fmaf(x1, wbv.w, fmaf(x2, wcv.w, bb.w))), 0.0f);
            #pragma unroll
            for (int u = 0; u < 4; ++u) {
                const float4* r = (const float4*)&w2[(jb * 4 + u) * 16];
                float4 r0 = r[0], r1 = r[1], r2 = r[2], r3 = r[3];
                float h = hh[u];
                o[0]  = fmaf(h, r0.x, o[0]);  o[1]  = fmaf(h, r0.y, o[1]);
                o[2]  = fmaf(h, r0.z, o[2]);  o[3]  = fmaf(h, r0.w, o[3]);
                o[4]  = fmaf(h, r1.x, o[4]);  o[5]  = fmaf(h, r1.y, o[5]);
                o[6]  = fmaf(h, r1.z, o[6]);  o[7]  = fmaf(h, r1.w, o[7]);
                o[8]  = fmaf(h, r2.x, o[8]);  o[9]  = fmaf(h, r2.y, o[9]);
                o[10] = fmaf(h, r2.z, o[10]); o[11] = fmaf(h, r2.w, o[11]);
                o[12] = fmaf(h, r3.x, o[12]); o[13] = fmaf(h, r3.y, o[13]);
                o[14] = fmaf(h, r3.z, o[14]); o[15] = fmaf(h, r3.w, o[15]);
            }
        }
        *sig_out = softplus_f(o[0]);
        #pragma unroll
        for (int k = 0; k < 15; ++k) s_geo16[k][si] = f2bf(o[1 + k]);
    };

    // ---- Phase A: coarse samples (128 threads, all active) ----
    float z_reg, sigma_reg;
    {
        float frac = (float)tid * (1.0f / 127.0f);
        z_reg = fmaf(span, frac, nearv);
        s_z[tid] = z_reg;
        float x0 = clamp1(fmaf(dx, z_reg, ox));
        float x1 = clamp1(fmaf(dy, z_reg, oy));
        float x2 = clamp1(fmaf(dz, z_reg, oz));
        density_mlp(x0, x1, x2, tid, &sigma_reg);
        s_sigma[tid] = sigma_reg;
    }
    __syncthreads();

    // ---- Phase B: coarse alpha weights (shuffle scan) ----
    {
        float delta = (tid < T - 1) ? (s_z[tid + 1] - z_reg) : sample_dist;
        float alpha = 1.0f - expf(-delta * sigma_reg);
        float inc = 1.0f - alpha + 1e-15f;
        #pragma unroll
        for (int off = 1; off < 64; off <<= 1) {
            float v = __shfl_up(inc, off);
            if (lane >= off) inc *= v;
        }
        if (lane == 63) s_tmp[wv] = inc;
        __syncthreads();
        float ex = __shfl_up(inc, 1);
        if (lane == 0) ex = 1.0f;
        if (wv == 1) ex *= s_tmp[0];
        s_wc[tid] = alpha * ex;
    }
    __syncthreads();

    // ---- Phase C: pdf -> cdf over w_coarse[1..126] + bins ----
    {
        float pv = (tid < 126) ? (s_wc[tid + 1] + 1e-5f) : 0.0f;
        float inc = pv;
        #pragma unroll
        for (int off = 1; off < 64; off <<= 1) {
            float v = __shfl_up(inc, off);
            if (lane >= off) inc += v;
        }
        if (lane == 63) s_tmp[2 + wv] = inc;
        __syncthreads();
        float tot = s_tmp[2] + s_tmp[3];
        float inv = 1.0f / tot;
        if (wv == 1) inc += s_tmp[2];
        if (tid < 126) s_cdf[tid + 1] = inc * inv;
        if (tid == 0)  s_cdf[0] = 0.0f;
        s_bins[tid] = (tid < 127) ? fmaf(0.5f, s_z[tid + 1] - z_reg, z_reg) : 0.0f;
    }
    __syncthreads();

    // ---- Phase D: inverse-CDF sampling + fine density (all active) ----
    {
        float u = (1.0f + 2.0f * (float)tid) * (1.0f / 256.0f);
        int lo = 0, hi = 127;
        while (lo < hi) { int mid = (lo + hi) >> 1; if (s_cdf[mid] <= u) lo = mid + 1; else hi = mid; }
        int below = lo - 1;
        int above = (lo < 127) ? lo : 126;
        float cg0 = s_cdf[below], cg1 = s_cdf[above];
        float bg0 = s_bins[below], bg1 = s_bins[above];
        float den = cg1 - cg0; if (den < 1e-5f) den = 1.0f;
        float tt2 = (u - cg0) / den;
        float nz = fmaf(tt2, bg1 - bg0, bg0);
        s_z[T + tid] = nz;
        float x0 = clamp1(fmaf(dx, nz, ox));
        float x1 = clamp1(fmaf(dy, nz, oy));
        float x2 = clamp1(fmaf(dz, nz, oz));
        float sg;
        density_mlp(x0, x1, x2, T + tid, &sg);
        s_sigma[T + tid] = sg;
    }
    __syncthreads();

    // ---- Phase E: stable merge (each thread places its coarse + fine item) ----
    {
        float vc = z_reg;
        int lo = 0, hi = U;
        while (lo < hi) { int mid = (lo + hi) >> 1; if (s_z[T + mid] < vc) lo = mid + 1; else hi = mid; }
        int rc = tid + lo;
        s_perm[rc] = tid; s_zs[rc] = vc;

        float vf = s_z[T + tid];
        lo = 0; hi = T;
        while (lo < hi) { int mid = (lo + hi) >> 1; if (s_z[mid] <= vf) lo = mid + 1; else hi = mid; }
        int rf = tid + lo;
        s_perm[rf] = T + tid; s_zs[rf] = vf;
    }
    __syncthreads();

    // ---- Phase F: final weights over 256 sorted samples (2 elems/thread) ----
    const int eA = wv * 64 + lane;         // chunk wv      (0..127)
    const int eB = 128 + wv * 64 + lane;   // chunk 2+wv    (128..255)
    float wA, wB, aA, aB;
    {
        float zA = s_zs[eA];
        float dA = s_zs[eA + 1] - zA;                       // eA+1 <= 128, valid
        float zB = s_zs[eB];
        float dB = (eB < TT - 1) ? (s_zs[eB + 1] - zB) : sample_dist;
        aA = 1.0f - expf(-dA * s_sigma[s_perm[eA]]);
        aB = 1.0f - expf(-dB * s_sigma[s_perm[eB]]);
        float tA = 1.0f - aA + 1e-15f;
        float tB = 1.0f - aB + 1e-15f;
        #pragma unroll
        for (int off = 1; off < 64; off <<= 1) {
            float vA = __shfl_up(tA, off);
            float vB = __shfl_up(tB, off);
            if (lane >= off) { tA *= vA; tB *= vB; }
        }
        if (lane == 63) { s_ct[wv] = tA; s_ct[2 + wv] = tB; }
        __syncthreads();
        float ct0 = s_ct[0], ct1 = s_ct[1], ct2 = s_ct[2];
        float exA = __shfl_up(tA, 1); if (lane == 0) exA = 1.0f;
        float exB = __shfl_up(tB, 1); if (lane == 0) exB = 1.0f;
        float pA = (wv == 0) ? 1.0f : ct0;
        float pB = ct0 * ct1 * ((wv == 0) ? 1.0f : ct2);
        wA = aA * exA * pA;
        wB = aB * exB * pB;
    }

    // ---- Phase G: color MLP, 2 samples/thread (R=2 weight reuse) ----
    float inA[20], inB[20];
    inA[0] = dx; inA[1] = dy; inA[2] = dz;
    inB[0] = dx; inB[1] = dy; inB[2] = dz;
    {
        int pa = s_perm[eA], pb = s_perm[eB];
        #pragma unroll
        for (int k = 0; k < 15; ++k) {
            inA[3 + k] = bf2f(s_geo16[k][pa]);
            inB[3 + k] = bf2f(s_geo16[k][pb]);
        }
    }
    inA[18] = 1.0f; inA[19] = 0.0f;   // bias slot, pad
    inB[18] = 1.0f; inB[19] = 0.0f;
    float o0A = bc2[0], o1A = bc2[1], o2A = bc2[2];
    float o0B = o0A, o1B = o1A, o2B = o2A;
    for (int j = 0; j < 64; ++j) {
        const float4* row = (const float4*)&c1[j * 20];
        float hA = 0.0f, hB = 0.0f;
        #pragma unroll
        for (int kb = 0; kb < 5; ++kb) {
            float4 rr = row[kb];
            hA = fmaf(inA[kb * 4 + 0], rr.x, hA);
            hA = fmaf(inA[kb * 4 + 1], rr.y, hA);
            hA = fmaf(inA[kb * 4 + 2], rr.z, hA);
            hA = fmaf(inA[kb * 4 + 3], rr.w, hA);
            hB = fmaf(inB[kb * 4 + 0], rr.x, hB);
            hB = fmaf(inB[kb * 4 + 1], rr.y, hB);
            hB = fmaf(inB[kb * 4 + 2], rr.z, hB);
            hB = fmaf(inB[kb * 4 + 3], rr.w, hB);
        }
        hA = fmaxf(hA, 0.0f);
        hB = fmaxf(hB, 0.0f);
        float4 q = *(const float4*)&c2[j * 4];
        o0A = fmaf(hA, q.x, o0A); o1A = fmaf(hA, q.y, o1A); o2A = fmaf(hA, q.z, o2A);
        o0B = fmaf(hB, q.x, o0B); o1B = fmaf(hB, q.y, o1B); o2B = fmaf(hB, q.z, o2B);
    }
    float rA = sigmoid_f(o0A), gA = sigmoid_f(o1A), bA = sigmoid_f(o2A);
    float rB = sigmoid_f(o0B), gB = sigmoid_f(o1B), bB = sigmoid_f(o2B);

    // ---- Phase H: weighted reductions ----
    float orizA = fminf(fmaxf((s_zs[eA] - nearv) / span, 0.0f), 1.0f);
    float orizB = fminf(fmaxf((s_zs[eB] - nearv) / span, 0.0f), 1.0f);
    float c_ws = wA + wB;
    float c_dp = wA * orizA + wB * orizB;
    float c_r  = wA * rA + wB * rB;
    float c_g  = wA * gA + wB * gB;
    float c_b  = wA * bA + wB * bB;
    #pragma unroll
    for (int off = 32; off > 0; off >>= 1) {
        c_ws += __shfl_down(c_ws, off);
        c_dp += __shfl_down(c_dp, off);
        c_r  += __shfl_down(c_r,  off);
        c_g  += __shfl_down(c_g,  off);
        c_b  += __shfl_down(c_b,  off);
    }
    __syncthreads();
    if (lane == 0) {
        s_red[wv][0] = c_ws; s_red[wv][1] = c_dp;
        s_red[wv][2] = c_r;  s_red[wv][3] = c_g; s_red[wv][4] = c_b;
    }
    __syncthreads();
    if (tid == 0) {
        float ws = s_red[0][0] + s_red[1][0];
        float dp = s_red[0][1] + s_red[1][1];
        float rr = s_red[0][2] + s_red[1][2];
        float gg = s_red[0][3] + s_red[1][3];
        float bb = s_red[0][4] + s_red[1][4];
        float bgadd = 1.0f - ws;
        out[ray]             = dp;
        out[N + ray * 3 + 0] = rr + bgadd;
        out[N + ray * 3 + 1] = gg + bgadd;
        out[N + ray * 3 + 2] = bb + bgadd;
        out[4 * N + ray]     = ws;
    }
}

extern "C" void kernel_launch(void* const* d_in, const int* in_sizes, int n_in,
                              void* d_out, int out_size, void* d_ws, size_t ws_size,
                              hipStream_t stream) {
    const float* rays_o = (const float*)d_in[0];
    const float* rays_d = (const float*)d_in[1];
    const float* Wd1 = (const float*)d_in[2];
    const float* bd1 = (const float*)d_in[3];
    const float* Wd2 = (const float*)d_in[4];
    const float* bd2 = (const float*)d_in[5];
    const float* Wc1 = (const float*)d_in[6];
    const float* bc1 = (const float*)d_in[7];
    const float* Wc2 = (const float*)d_in[8];
    const float* bc2 = (const float*)d_in[9];

    const int N = in_sizes[0] / 3;   // 32768 rays
    float* out = (float*)d_out;

    nerf_render_kernel<<<N, NTH, 0, stream>>>(
        rays_o, rays_d, Wd1, bd1, Wd2, bd2, Wc1, bc1, Wc2, bc2, out, N);
}

// Round 14
// 702.975 us; speedup vs baseline: 6.1148x; 1.1397x over previous
//
#include <hip/hip_runtime.h>
#include <math.h>

#define NTH 256    // threads per block (2 rays x 128)
#define RPB 2      // rays per block
#define T 128      // num_steps
#define U 128      // upsample_steps
#define TT 256     // merged samples

__device__ __forceinline__ float softplus_f(float x) {
    return fmaxf(x, 0.0f) + log1pf(expf(-fabsf(x)));
}
__device__ __forceinline__ float sigmoid_f(float x) {
    return 1.0f / (1.0f + expf(-x));
}
__device__ __forceinline__ float clamp1(float x) {
    return fminf(fmaxf(x, -1.0f), 1.0f);
}
// fp32 -> bf16 (RNE) and back
__device__ __forceinline__ unsigned short f2bf(float f) {
    unsigned int u = __float_as_uint(f);
    unsigned int r = (u + 0x7FFFu + ((u >> 16) & 1u)) >> 16;
    return (unsigned short)r;
}
__device__ __forceinline__ float bf2f(unsigned short v) {
    return __uint_as_float(((unsigned int)v) << 16);
}

__global__ void __launch_bounds__(NTH)
nerf_render_kernel(
    const float* __restrict__ rays_o, const float* __restrict__ rays_d,
    const float* __restrict__ Wd1, const float* __restrict__ bd1,
    const float* __restrict__ Wd2, const float* __restrict__ bd2,
    const float* __restrict__ Wc1, const float* __restrict__ bc1,
    const float* __restrict__ Wc2, const float* __restrict__ bc2,
    float* __restrict__ out, int N)
{
    const int tid  = threadIdx.x;
    const int rtid = tid & 127;          // thread within ray
    const int r    = tid >> 7;           // ray slot 0/1
    const int ray  = blockIdx.x * RPB + r;
    const int lane = tid & 63;
    const int wv   = (tid >> 6) & 1;     // wave within ray

    // ---- LDS: weights (shared by both rays) + per-ray state ----
    __shared__ float w1[192];        // Wd1 [3][64] as-is
    __shared__ float b1[64];
    __shared__ float w2[1024];       // Wd2 [64][16] as-is
    __shared__ float b2[16];
    __shared__ float c1[64 * 20];    // row j: Wc1[k][j] k=0..17, bias at [18], 0 at [19]
    __shared__ float c2[64 * 4];     // row j: Wc2[j][0..2], 0
    __shared__ unsigned short s_geo16[RPB][15][TT];  // bf16 geo, column-major per ray
    __shared__ float s_sigma[RPB][TT];
    __shared__ float s_z[RPB][TT];   // [0..127] coarse, [128..255] fine
    __shared__ float s_zs[RPB][TT];  // sorted
    __shared__ int   s_perm[RPB][TT];
    __shared__ float s_wc[RPB][T];
    __shared__ float s_cdf[RPB][T];  // 0..126 used
    __shared__ float s_bins[RPB][T]; // 0..126 used
    __shared__ float s_ct[RPB][4];   // chunk totals (final scan)
    __shared__ float s_tmp[RPB][4];  // wave totals (coarse scans)
    __shared__ float s_red[RPB][2][5];

    // ---- stage weights into LDS (coalesced, once per block, both rays) ----
    for (int i = tid; i < 192; i += NTH)  w1[i] = Wd1[i];
    for (int i = tid; i < 64; i += NTH)   b1[i] = bd1[i];
    for (int i = tid; i < 1024; i += NTH) w2[i] = Wd2[i];
    for (int i = tid; i < 16; i += NTH)   b2[i] = bd2[i];
    for (int i = tid; i < 64 * 20; i += NTH) {
        int j = i / 20, k = i - j * 20;
        c1[i] = (k < 18) ? Wc1[k * 64 + j] : ((k == 18) ? bc1[j] : 0.0f);
    }
    for (int i = tid; i < 256; i += NTH) {
        int j = i >> 2, c = i & 3;
        c2[i] = (c < 3) ? Wc2[j * 3 + c] : 0.0f;
    }

    // ---- ray data + slab test (uniform per 128-thread half) ----
    const float ox = rays_o[ray * 3 + 0], oy = rays_o[ray * 3 + 1], oz = rays_o[ray * 3 + 2];
    const float dx = rays_d[ray * 3 + 0], dy = rays_d[ray * 3 + 1], dz = rays_d[ray * 3 + 2];
    const float ivx = 1.0f / dx, ivy = 1.0f / dy, ivz = 1.0f / dz;
    const float t1x = (-1.0f - ox) * ivx, t2x = (1.0f - ox) * ivx;
    const float t1y = (-1.0f - oy) * ivy, t2y = (1.0f - oy) * ivy;
    const float t1z = (-1.0f - oz) * ivz, t2z = (1.0f - oz) * ivz;
    const float tmin = fmaxf(fmaxf(fminf(t1x, t2x), fminf(t1y, t2y)), fminf(t1z, t2z));
    const float tmax = fminf(fminf(fmaxf(t1x, t2x), fmaxf(t1y, t2y)), fmaxf(t1z, t2z));
    const float nearv = fmaxf(tmin, 0.2f);
    const float farv  = fmaxf(tmax, nearv + 1e-4f);
    const float span  = farv - nearv;
    const float sample_dist = span * (1.0f / 128.0f);

    __syncthreads();   // weights staged

    // fused density MLP: LDS-broadcast weights, layer1+layer2 chunk-fused.
    // geo written directly to bf16 column-major LDS for sample index si, ray slot r.
    auto density_mlp = [&](float x0, float x1, float x2, int si, float* sig_out) {
        float o[16];
        {
            const float4* bp = (const float4*)b2;
            float4 q0 = bp[0], q1 = bp[1], q2 = bp[2], q3 = bp[3];
            o[0] = q0.x; o[1] = q0.y; o[2]  = q0.z; o[3]  = q0.w;
            o[4] = q1.x; o[5] = q1.y; o[6]  = q1.z; o[7]  = q1.w;
            o[8] = q2.x; o[9] = q2.y; o[10] = q2.z; o[11] = q2.w;
            o[12] = q3.x; o[13] = q3.y; o[14] = q3.z; o[15] = q3.w;
        }
        for (int jb = 0; jb < 16; ++jb) {   // not fully unrolled: keep icache small
            float4 wa  = *(const float4*)&w1[jb * 4];
            float4 wbv = *(const float4*)&w1[64 + jb * 4];
            float4 wcv = *(const float4*)&w1[128 + jb * 4];
            float4 bb  = *(const float4*)&b1[jb * 4];
            float hh[4];
            hh[0] = fmaxf(fmaf(x0, wa.x, fmaf(x1, wbv.x, fmaf(x2, wcv.x, bb.x))), 0.0f);
            hh[1] = fmaxf(fmaf(x0, wa.y, fmaf(x1, wbv.y, fmaf(x2, wcv.y, bb.y))), 0.0f);
            hh[2] = fmaxf(fmaf(x0, wa.z, fmaf(x1, wbv.z, fmaf(x2, wcv.z, bb.z))), 0.0f);
            hh[3] = fmaxf(fmaf(x0, wa.w, fmaf(x1, wbv.w, fmaf(x2, wcv.w, bb.w))), 0.0f);
            #pragma unroll
            for (int u = 0; u < 4; ++u) {
                const float4* rr = (const float4*)&w2[(jb * 4 + u) * 16];
                float4 r0 = rr[0], r1 = rr[1], r2 = rr[2], r3 = rr[3];
                float h = hh[u];
                o[0]  = fmaf(h, r0.x, o[0]);  o[1]  = fmaf(h, r0.y, o[1]);
                o[2]  = fmaf(h, r0.z, o[2]);  o[3]  = fmaf(h, r0.w, o[3]);
                o[4]  = fmaf(h, r1.x, o[4]);  o[5]  = fmaf(h, r1.y, o[5]);
                o[6]  = fmaf(h, r1.z, o[6]);  o[7]  = fmaf(h, r1.w, o[7]);
                o[8]  = fmaf(h, r2.x, o[8]);  o[9]  = fmaf(h, r2.y, o[9]);
                o[10] = fmaf(h, r2.z, o[10]); o[11] = fmaf(h, r2.w, o[11]);
                o[12] = fmaf(h, r3.x, o[12]); o[13] = fmaf(h, r3.y, o[13]);
                o[14] = fmaf(h, r3.z, o[14]); o[15] = fmaf(h, r3.w, o[15]);
            }
        }
        *sig_out = softplus_f(o[0]);
        #pragma unroll
        for (int k = 0; k < 15; ++k) s_geo16[r][k][si] = f2bf(o[1 + k]);
    };

    // ---- Phase A: coarse samples (all 128 per-ray threads active) ----
    float z_reg, sigma_reg;
    {
        float frac = (float)rtid * (1.0f / 127.0f);
        z_reg = fmaf(span, frac, nearv);
        s_z[r][rtid] = z_reg;
        float x0 = clamp1(fmaf(dx, z_reg, ox));
        float x1 = clamp1(fmaf(dy, z_reg, oy));
        float x2 = clamp1(fmaf(dz, z_reg, oz));
        density_mlp(x0, x1, x2, rtid, &sigma_reg);
        s_sigma[r][rtid] = sigma_reg;
    }
    __syncthreads();

    // ---- Phase B: coarse alpha weights (shuffle scan) ----
    {
        float delta = (rtid < T - 1) ? (s_z[r][rtid + 1] - z_reg) : sample_dist;
        float alpha = 1.0f - expf(-delta * sigma_reg);
        float inc = 1.0f - alpha + 1e-15f;
        #pragma unroll
        for (int off = 1; off < 64; off <<= 1) {
            float v = __shfl_up(inc, off);
            if (lane >= off) inc *= v;
        }
        if (lane == 63) s_tmp[r][wv] = inc;
        __syncthreads();
        float ex = __shfl_up(inc, 1);
        if (lane == 0) ex = 1.0f;
        if (wv == 1) ex *= s_tmp[r][0];
        s_wc[r][rtid] = alpha * ex;
    }
    __syncthreads();

    // ---- Phase C: pdf -> cdf over w_coarse[1..126] + bins ----
    {
        float pv = (rtid < 126) ? (s_wc[r][rtid + 1] + 1e-5f) : 0.0f;
        float inc = pv;
        #pragma unroll
        for (int off = 1; off < 64; off <<= 1) {
            float v = __shfl_up(inc, off);
            if (lane >= off) inc += v;
        }
        if (lane == 63) s_tmp[r][2 + wv] = inc;
        __syncthreads();
        float tot = s_tmp[r][2] + s_tmp[r][3];
        float inv = 1.0f / tot;
        if (wv == 1) inc += s_tmp[r][2];
        if (rtid < 126) s_cdf[r][rtid + 1] = inc * inv;
        if (rtid == 0)  s_cdf[r][0] = 0.0f;
        s_bins[r][rtid] = (rtid < 127) ? fmaf(0.5f, s_z[r][rtid + 1] - z_reg, z_reg) : 0.0f;
    }
    __syncthreads();

    // ---- Phase D: inverse-CDF sampling + fine density (all active) ----
    {
        float u = (1.0f + 2.0f * (float)rtid) * (1.0f / 256.0f);
        int lo = 0, hi = 127;
        while (lo < hi) { int mid = (lo + hi) >> 1; if (s_cdf[r][mid] <= u) lo = mid + 1; else hi = mid; }
        int below = lo - 1;
        int above = (lo < 127) ? lo : 126;
        float cg0 = s_cdf[r][below], cg1 = s_cdf[r][above];
        float bg0 = s_bins[r][below], bg1 = s_bins[r][above];
        float den = cg1 - cg0; if (den < 1e-5f) den = 1.0f;
        float tt2 = (u - cg0) / den;
        float nz = fmaf(tt2, bg1 - bg0, bg0);
        s_z[r][T + rtid] = nz;
        float x0 = clamp1(fmaf(dx, nz, ox));
        float x1 = clamp1(fmaf(dy, nz, oy));
        float x2 = clamp1(fmaf(dz, nz, oz));
        float sg;
        density_mlp(x0, x1, x2, T + rtid, &sg);
        s_sigma[r][T + rtid] = sg;
    }
    __syncthreads();

    // ---- Phase E: stable merge (each thread places its coarse + fine item) ----
    {
        float vc = z_reg;
        int lo = 0, hi = U;
        while (lo < hi) { int mid = (lo + hi) >> 1; if (s_z[r][T + mid] < vc) lo = mid + 1; else hi = mid; }
        int rc = rtid + lo;
        s_perm[r][rc] = rtid; s_zs[r][rc] = vc;

        float vf = s_z[r][T + rtid];
        lo = 0; hi = T;
        while (lo < hi) { int mid = (lo + hi) >> 1; if (s_z[r][mid] <= vf) lo = mid + 1; else hi = mid; }
        int rf = rtid + lo;
        s_perm[r][rf] = T + rtid; s_zs[r][rf] = vf;
    }
    __syncthreads();

    // ---- Phase F: final weights over 256 sorted samples (2 elems/thread) ----
    const int eA = wv * 64 + lane;         // chunk wv      (0..127)
    const int eB = 128 + wv * 64 + lane;   // chunk 2+wv    (128..255)
    float wA, wB, aA, aB;
    {
        float zA = s_zs[r][eA];
        float dA = s_zs[r][eA + 1] - zA;                    // eA+1 <= 128, valid
        float zB = s_zs[r][eB];
        float dB = (eB < TT - 1) ? (s_zs[r][eB + 1] - zB) : sample_dist;
        aA = 1.0f - expf(-dA * s_sigma[r][s_perm[r][eA]]);
        aB = 1.0f - expf(-dB * s_sigma[r][s_perm[r][eB]]);
        float tA = 1.0f - aA + 1e-15f;
        float tB = 1.0f - aB + 1e-15f;
        #pragma unroll
        for (int off = 1; off < 64; off <<= 1) {
            float vA = __shfl_up(tA, off);
            float vB = __shfl_up(tB, off);
            if (lane >= off) { tA *= vA; tB *= vB; }
        }
        if (lane == 63) { s_ct[r][wv] = tA; s_ct[r][2 + wv] = tB; }
        __syncthreads();
        float ct0 = s_ct[r][0], ct1 = s_ct[r][1], ct2 = s_ct[r][2];
        float exA = __shfl_up(tA, 1); if (lane == 0) exA = 1.0f;
        float exB = __shfl_up(tB, 1); if (lane == 0) exB = 1.0f;
        float pA = (wv == 0) ? 1.0f : ct0;
        float pB = ct0 * ct1 * ((wv == 0) ? 1.0f : ct2);
        wA = aA * exA * pA;
        wB = aB * exB * pB;
    }

    // ---- Phase G: color MLP, 2 samples/thread (R=2 weight reuse) ----
    float inA[20], inB[20];
    inA[0] = dx; inA[1] = dy; inA[2] = dz;
    inB[0] = dx; inB[1] = dy; inB[2] = dz;
    {
        int pa = s_perm[r][eA], pb = s_perm[r][eB];
        #pragma unroll
        for (int k = 0; k < 15; ++k) {
            inA[3 + k] = bf2f(s_geo16[r][k][pa]);
            inB[3 + k] = bf2f(s_geo16[r][k][pb]);
        }
    }
    inA[18] = 1.0f; inA[19] = 0.0f;   // bias slot, pad
    inB[18] = 1.0f; inB[19] = 0.0f;
    float o0A = bc2[0], o1A = bc2[1], o2A = bc2[2];
    float o0B = o0A, o1B = o1A, o2B = o2A;
    for (int j = 0; j < 64; ++j) {
        const float4* row = (const float4*)&c1[j * 20];
        float hA = 0.0f, hB = 0.0f;
        #pragma unroll
        for (int kb = 0; kb < 5; ++kb) {
            float4 rr = row[kb];
            hA = fmaf(inA[kb * 4 + 0], rr.x, hA);
            hA = fmaf(inA[kb * 4 + 1], rr.y, hA);
            hA = fmaf(inA[kb * 4 + 2], rr.z, hA);
            hA = fmaf(inA[kb * 4 + 3], rr.w, hA);
            hB = fmaf(inB[kb * 4 + 0], rr.x, hB);
            hB = fmaf(inB[kb * 4 + 1], rr.y, hB);
            hB = fmaf(inB[kb * 4 + 2], rr.z, hB);
            hB = fmaf(inB[kb * 4 + 3], rr.w, hB);
        }
        hA = fmaxf(hA, 0.0f);
        hB = fmaxf(hB, 0.0f);
        float4 q = *(const float4*)&c2[j * 4];
        o0A = fmaf(hA, q.x, o0A); o1A = fmaf(hA, q.y, o1A); o2A = fmaf(hA, q.z, o2A);
        o0B = fmaf(hB, q.x, o0B); o1B = fmaf(hB, q.y, o1B); o2B = fmaf(hB, q.z, o2B);
    }
    float rA = sigmoid_f(o0A), gA = sigmoid_f(o1A), bA = sigmoid_f(o2A);
    float rB = sigmoid_f(o0B), gB = sigmoid_f(o1B), bB = sigmoid_f(o2B);

    // ---- Phase H: weighted reductions ----
    float orizA = fminf(fmaxf((s_zs[r][eA] - nearv) / span, 0.0f), 1.0f);
    float orizB = fminf(fmaxf((s_zs[r][eB] - nearv) / span, 0.0f), 1.0f);
    float c_ws = wA + wB;
    float c_dp = wA * orizA + wB * orizB;
    float c_r  = wA * rA + wB * rB;
    float c_g  = wA * gA + wB * gB;
    float c_b  = wA * bA + wB * bB;
    #pragma unroll
    for (int off = 32; off > 0; off >>= 1) {
        c_ws += __shfl_down(c_ws, off);
        c_dp += __shfl_down(c_dp, off);
        c_r  += __shfl_down(c_r,  off);
        c_g  += __shfl_down(c_g,  off);
        c_b  += __shfl_down(c_b,  off);
    }
    __syncthreads();
    if (lane == 0) {
        s_red[r][wv][0] = c_ws; s_red[r][wv][1] = c_dp;
        s_red[r][wv][2] = c_r;  s_red[r][wv][3] = c_g; s_red[r][wv][4] = c_b;
    }
    __syncthreads();
    if (rtid == 0) {
        float ws = s_red[r][0][0] + s_red[r][1][0];
        float dp = s_red[r][0][1] + s_red[r][1][1];
        float rr = s_red[r][0][2] + s_red[r][1][2];
        float gg = s_red[r][0][3] + s_red[r][1][3];
        float bb = s_red[r][0][4] + s_red[r][1][4];
        float bgadd = 1.0f - ws;
        out[ray]             = dp;
        out[N + ray * 3 + 0] = rr + bgadd;
        out[N + ray * 3 + 1] = gg + bgadd;
        out[N + ray * 3 + 2] = bb + bgadd;
        out[4 * N + ray]     = ws;
    }
}

extern "C" void kernel_launch(void* const* d_in, const int* in_sizes, int n_in,
                              void* d_out, int out_size, void* d_ws, size_t ws_size,
                              hipStream_t stream) {
    const float* rays_o = (const float*)d_in[0];
    const float* rays_d = (const float*)d_in[1];
    const float* Wd1 = (const float*)d_in[2];
    const float* bd1 = (const float*)d_in[3];
    const float* Wd2 = (const float*)d_in[4];
    const float* bd2 = (const float*)d_in[5];
    const float* Wc1 = (const float*)d_in[6];
    const float* bc1 = (const float*)d_in[7];
    const float* Wc2 = (const float*)d_in[8];
    const float* bc2 = (const float*)d_in[9];

    const int N = in_sizes[0] / 3;   // 32768 rays
    float* out = (float*)d_out;

    nerf_render_kernel<<<N / RPB, NTH, 0, stream>>>(
        rays_o, rays_d, Wd1, bd1, Wd2, bd2, Wc1, bc1, Wc2, bc2, out, N);
}

// Round 16
// 616.697 us; speedup vs baseline: 6.9703x; 1.1399x over previous
//
#include <hip/hip_runtime.h>
#include <math.h>

#define NTH 256    // threads per block (2 rays x 128)
#define RPB 2      // rays per block
#define T 128      // num_steps
#define U 128      // upsample_steps
#define TT 256     // merged samples

__device__ __forceinline__ float softplus_f(float x) {
    return fmaxf(x, 0.0f) + log1pf(expf(-fabsf(x)));
}
__device__ __forceinline__ float sigmoid_f(float x) {
    return 1.0f / (1.0f + expf(-x));
}
__device__ __forceinline__ float clamp1(float x) {
    return fminf(fmaxf(x, -1.0f), 1.0f);
}
// fp32 -> bf16 (RNE) and back
__device__ __forceinline__ unsigned short f2bf(float f) {
    unsigned int u = __float_as_uint(f);
    unsigned int r = (u + 0x7FFFu + ((u >> 16) & 1u)) >> 16;
    return (unsigned short)r;
}
__device__ __forceinline__ float bf2f(unsigned short v) {
    return __uint_as_float(((unsigned int)v) << 16);
}

__global__ void __launch_bounds__(NTH, 5)
nerf_render_kernel(
    const float* __restrict__ rays_o, const float* __restrict__ rays_d,
    const float* __restrict__ Wd1, const float* __restrict__ bd1,
    const float* __restrict__ Wd2, const float* __restrict__ bd2,
    const float* __restrict__ Wc1, const float* __restrict__ bc1,
    const float* __restrict__ Wc2, const float* __restrict__ bc2,
    float* __restrict__ out, int N)
{
    const int tid  = threadIdx.x;
    const int rtid = tid & 127;          // thread within ray
    const int r    = tid >> 7;           // ray slot 0/1
    const int ray  = blockIdx.x * RPB + r;
    const int lane = tid & 63;
    const int wv   = (tid >> 6) & 1;     // wave within ray

    // ---- LDS: per-ray state only (weights come via scalar loads) ----
    __shared__ unsigned short s_geo16[RPB][15][TT];  // bf16 geo, column-major per ray
    __shared__ float s_sigma[RPB][TT];
    __shared__ float s_z[RPB][TT];   // [0..127] coarse, [128..255] fine
    __shared__ float s_zs[RPB][TT];  // sorted
    __shared__ int   s_perm[RPB][TT];
    __shared__ float s_wc[RPB][T];
    __shared__ float s_cdf[RPB][T];  // 0..126 used
    __shared__ float s_bins[RPB][T]; // 0..126 used
    __shared__ float s_ct[RPB][4];   // chunk totals (final scan)
    __shared__ float s_tmp[RPB][4];  // wave totals (coarse scans)
    __shared__ float s_red[RPB][2][5];

    // ---- ray data + slab test (uniform per 128-thread half) ----
    const float ox = rays_o[ray * 3 + 0], oy = rays_o[ray * 3 + 1], oz = rays_o[ray * 3 + 2];
    const float dx = rays_d[ray * 3 + 0], dy = rays_d[ray * 3 + 1], dz = rays_d[ray * 3 + 2];
    const float ivx = 1.0f / dx, ivy = 1.0f / dy, ivz = 1.0f / dz;
    const float t1x = (-1.0f - ox) * ivx, t2x = (1.0f - ox) * ivx;
    const float t1y = (-1.0f - oy) * ivy, t2y = (1.0f - oy) * ivy;
    const float t1z = (-1.0f - oz) * ivz, t2z = (1.0f - oz) * ivz;
    const float tmin = fmaxf(fmaxf(fminf(t1x, t2x), fminf(t1y, t2y)), fminf(t1z, t2z));
    const float tmax = fminf(fminf(fmaxf(t1x, t2x), fmaxf(t1y, t2y)), fmaxf(t1z, t2z));
    const float nearv = fmaxf(tmin, 0.2f);
    const float farv  = fmaxf(tmax, nearv + 1e-4f);
    const float span  = farv - nearv;
    const float sample_dist = span * (1.0f / 128.0f);

    // fused density MLP: weights via uniform (scalar) global loads, SGPR operands.
    // geo written directly to bf16 column-major LDS for sample index si, ray slot r.
    auto density_mlp = [&](float x0, float x1, float x2, int si, float* sig_out) {
        float o[16];
        #pragma unroll
        for (int m = 0; m < 16; ++m) o[m] = bd2[m];
        for (int jb = 0; jb < 16; ++jb) {   // rolled: per-iter s_load batches
            float hh[4];
            #pragma unroll
            for (int q = 0; q < 4; ++q) {
                int j = jb * 4 + q;
                hh[q] = fmaxf(fmaf(x0, Wd1[j], fmaf(x1, Wd1[64 + j], fmaf(x2, Wd1[128 + j], bd1[j]))), 0.0f);
            }
            #pragma unroll
            for (int u = 0; u < 4; ++u) {
                float h = hh[u];
                #pragma unroll
                for (int m = 0; m < 16; ++m)
                    o[m] = fmaf(h, Wd2[(jb * 4 + u) * 16 + m], o[m]);
            }
        }
        *sig_out = softplus_f(o[0]);
        #pragma unroll
        for (int k = 0; k < 15; ++k) s_geo16[r][k][si] = f2bf(o[1 + k]);
    };

    // ---- Phase A: coarse samples (all 128 per-ray threads active) ----
    float z_reg, sigma_reg;
    {
        float frac = (float)rtid * (1.0f / 127.0f);
        z_reg = fmaf(span, frac, nearv);
        s_z[r][rtid] = z_reg;
        float x0 = clamp1(fmaf(dx, z_reg, ox));
        float x1 = clamp1(fmaf(dy, z_reg, oy));
        float x2 = clamp1(fmaf(dz, z_reg, oz));
        density_mlp(x0, x1, x2, rtid, &sigma_reg);
        s_sigma[r][rtid] = sigma_reg;
    }
    __syncthreads();

    // ---- Phase B: coarse alpha weights (shuffle scan) ----
    {
        float delta = (rtid < T - 1) ? (s_z[r][rtid + 1] - z_reg) : sample_dist;
        float alpha = 1.0f - expf(-delta * sigma_reg);
        float inc = 1.0f - alpha + 1e-15f;
        #pragma unroll
        for (int off = 1; off < 64; off <<= 1) {
            float v = __shfl_up(inc, off);
            if (lane >= off) inc *= v;
        }
        if (lane == 63) s_tmp[r][wv] = inc;
        __syncthreads();
        float ex = __shfl_up(inc, 1);
        if (lane == 0) ex = 1.0f;
        if (wv == 1) ex *= s_tmp[r][0];
        s_wc[r][rtid] = alpha * ex;
    }
    __syncthreads();

    // ---- Phase C: pdf -> cdf over w_coarse[1..126] + bins ----
    {
        float pv = (rtid < 126) ? (s_wc[r][rtid + 1] + 1e-5f) : 0.0f;
        float inc = pv;
        #pragma unroll
        for (int off = 1; off < 64; off <<= 1) {
            float v = __shfl_up(inc, off);
            if (lane >= off) inc += v;
        }
        if (lane == 63) s_tmp[r][2 + wv] = inc;
        __syncthreads();
        float tot = s_tmp[r][2] + s_tmp[r][3];
        float inv = 1.0f / tot;
        if (wv == 1) inc += s_tmp[r][2];
        if (rtid < 126) s_cdf[r][rtid + 1] = inc * inv;
        if (rtid == 0)  s_cdf[r][0] = 0.0f;
        s_bins[r][rtid] = (rtid < 127) ? fmaf(0.5f, s_z[r][rtid + 1] - z_reg, z_reg) : 0.0f;
    }
    __syncthreads();

    // ---- Phase D: inverse-CDF sampling + fine density (all active) ----
    {
        float u = (1.0f + 2.0f * (float)rtid) * (1.0f / 256.0f);
        int lo = 0, hi = 127;
        while (lo < hi) { int mid = (lo + hi) >> 1; if (s_cdf[r][mid] <= u) lo = mid + 1; else hi = mid; }
        int below = lo - 1;
        int above = (lo < 127) ? lo : 126;
        float cg0 = s_cdf[r][below], cg1 = s_cdf[r][above];
        float bg0 = s_bins[r][below], bg1 = s_bins[r][above];
        float den = cg1 - cg0; if (den < 1e-5f) den = 1.0f;
        float tt2 = (u - cg0) / den;
        float nz = fmaf(tt2, bg1 - bg0, bg0);
        s_z[r][T + rtid] = nz;
        float x0 = clamp1(fmaf(dx, nz, ox));
        float x1 = clamp1(fmaf(dy, nz, oy));
        float x2 = clamp1(fmaf(dz, nz, oz));
        float sg;
        density_mlp(x0, x1, x2, T + rtid, &sg);
        s_sigma[r][T + rtid] = sg;
    }
    __syncthreads();

    // ---- Phase E: stable merge (each thread places its coarse + fine item) ----
    {
        float vc = z_reg;
        int lo = 0, hi = U;
        while (lo < hi) { int mid = (lo + hi) >> 1; if (s_z[r][T + mid] < vc) lo = mid + 1; else hi = mid; }
        int rc = rtid + lo;
        s_perm[r][rc] = rtid; s_zs[r][rc] = vc;

        float vf = s_z[r][T + rtid];
        lo = 0; hi = T;
        while (lo < hi) { int mid = (lo + hi) >> 1; if (s_z[r][mid] <= vf) lo = mid + 1; else hi = mid; }
        int rf = rtid + lo;
        s_perm[r][rf] = T + rtid; s_zs[r][rf] = vf;
    }
    __syncthreads();

    // ---- Phase F: final weights over 256 sorted samples (2 elems/thread) ----
    const int eA = wv * 64 + lane;         // chunk wv      (0..127)
    const int eB = 128 + wv * 64 + lane;   // chunk 2+wv    (128..255)
    float wA, wB, aA, aB;
    {
        float zA = s_zs[r][eA];
        float dA = s_zs[r][eA + 1] - zA;                    // eA+1 <= 128, valid
        float zB = s_zs[r][eB];
        float dB = (eB < TT - 1) ? (s_zs[r][eB + 1] - zB) : sample_dist;
        aA = 1.0f - expf(-dA * s_sigma[r][s_perm[r][eA]]);
        aB = 1.0f - expf(-dB * s_sigma[r][s_perm[r][eB]]);
        float tA = 1.0f - aA + 1e-15f;
        float tB = 1.0f - aB + 1e-15f;
        #pragma unroll
        for (int off = 1; off < 64; off <<= 1) {
            float vA = __shfl_up(tA, off);
            float vB = __shfl_up(tB, off);
            if (lane >= off) { tA *= vA; tB *= vB; }
        }
        if (lane == 63) { s_ct[r][wv] = tA; s_ct[r][2 + wv] = tB; }
        __syncthreads();
        float ct0 = s_ct[r][0], ct1 = s_ct[r][1], ct2 = s_ct[r][2];
        float exA = __shfl_up(tA, 1); if (lane == 0) exA = 1.0f;
        float exB = __shfl_up(tB, 1); if (lane == 0) exB = 1.0f;
        float pA = (wv == 0) ? 1.0f : ct0;
        float pB = ct0 * ct1 * ((wv == 0) ? 1.0f : ct2);
        wA = aA * exA * pA;
        wB = aB * exB * pB;
    }

    // ---- Phase G: color MLP, 2 samples/thread, weights via scalar loads ----
    float inA[18], inB[18];
    inA[0] = dx; inA[1] = dy; inA[2] = dz;
    inB[0] = dx; inB[1] = dy; inB[2] = dz;
    {
        int pa = s_perm[r][eA], pb = s_perm[r][eB];
        #pragma unroll
        for (int k = 0; k < 15; ++k) {
            inA[3 + k] = bf2f(s_geo16[r][k][pa]);
            inB[3 + k] = bf2f(s_geo16[r][k][pb]);
        }
    }
    float o0A = bc2[0], o1A = bc2[1], o2A = bc2[2];
    float o0B = o0A, o1B = o1A, o2B = o2A;
    for (int j4 = 0; j4 < 64; j4 += 4) {     // 4 units per group: s_load_dwordx4 rows
        float hA[4], hB[4];
        #pragma unroll
        for (int q = 0; q < 4; ++q) { hA[q] = bc1[j4 + q]; hB[q] = hA[q]; }
        #pragma unroll
        for (int k = 0; k < 18; ++k) {
            float a = inA[k], b = inB[k];
            #pragma unroll
            for (int q = 0; q < 4; ++q) {
                float w = Wc1[k * 64 + j4 + q];
                hA[q] = fmaf(a, w, hA[q]);
                hB[q] = fmaf(b, w, hB[q]);
            }
        }
        #pragma unroll
        for (int q = 0; q < 4; ++q) {
            float ha = fmaxf(hA[q], 0.0f), hb = fmaxf(hB[q], 0.0f);
            float w0 = Wc2[(j4 + q) * 3 + 0];
            float w1 = Wc2[(j4 + q) * 3 + 1];
            float w2 = Wc2[(j4 + q) * 3 + 2];
            o0A = fmaf(ha, w0, o0A); o1A = fmaf(ha, w1, o1A); o2A = fmaf(ha, w2, o2A);
            o0B = fmaf(hb, w0, o0B); o1B = fmaf(hb, w1, o1B); o2B = fmaf(hb, w2, o2B);
        }
    }
    float rA = sigmoid_f(o0A), gA = sigmoid_f(o1A), bA = sigmoid_f(o2A);
    float rB = sigmoid_f(o0B), gB = sigmoid_f(o1B), bB = sigmoid_f(o2B);

    // ---- Phase H: weighted reductions ----
    float orizA = fminf(fmaxf((s_zs[r][eA] - nearv) / span, 0.0f), 1.0f);
    float orizB = fminf(fmaxf((s_zs[r][eB] - nearv) / span, 0.0f), 1.0f);
    float c_ws = wA + wB;
    float c_dp = wA * orizA + wB * orizB;
    float c_r  = wA * rA + wB * rB;
    float c_g  = wA * gA + wB * gB;
    float c_b  = wA * bA + wB * bB;
    #pragma unroll
    for (int off = 32; off > 0; off >>= 1) {
        c_ws += __shfl_down(c_ws, off);
        c_dp += __shfl_down(c_dp, off);
        c_r  += __shfl_down(c_r,  off);
        c_g  += __shfl_down(c_g,  off);
        c_b  += __shfl_down(c_b,  off);
    }
    __syncthreads();
    if (lane == 0) {
        s_red[r][wv][0] = c_ws; s_red[r][wv][1] = c_dp;
        s_red[r][wv][2] = c_r;  s_red[r][wv][3] = c_g; s_red[r][wv][4] = c_b;
    }
    __syncthreads();
    if (rtid == 0) {
        float ws = s_red[r][0][0] + s_red[r][1][0];
        float dp = s_red[r][0][1] + s_red[r][1][1];
        float rr = s_red[r][0][2] + s_red[r][1][2];
        float gg = s_red[r][0][3] + s_red[r][1][3];
        float bb = s_red[r][0][4] + s_red[r][1][4];
        float bgadd = 1.0f - ws;
        out[ray]             = dp;
        out[N + ray * 3 + 0] = rr + bgadd;
        out[N + ray * 3 + 1] = gg + bgadd;
        out[N + ray * 3 + 2] = bb + bgadd;
        out[4 * N + ray]     = ws;
    }
}

extern "C" void kernel_launch(void* const* d_in, const int* in_sizes, int n_in,
                              void* d_out, int out_size, void* d_ws, size_t ws_size,
                              hipStream_t stream) {
    const float* rays_o = (const float*)d_in[0];
    const float* rays_d = (const float*)d_in[1];
    const float* Wd1 = (const float*)d_in[2];
    const float* bd1 = (const float*)d_in[3];
    const float* Wd2 = (const float*)d_in[4];
    const float* bd2 = (const float*)d_in[5];
    const float* Wc1 = (const float*)d_in[6];
    const float* bc1 = (const float*)d_in[7];
    const float* Wc2 = (const float*)d_in[8];
    const float* bc2 = (const float*)d_in[9];

    const int N = in_sizes[0] / 3;   // 32768 rays
    float* out = (float*)d_out;

    nerf_render_kernel<<<N / RPB, NTH, 0, stream>>>(
        rays_o, rays_d, Wd1, bd1, Wd2, bd2, Wc1, bc1, Wc2, bc2, out, N);
}